// Round 1
// baseline (572.820 us; speedup 1.0000x reference)
//
#include <hip/hip_runtime.h>
#include <hip/hip_bf16.h>
#include <math.h>

#define B_ 8
#define C_ 128
#define P_ 100000
#define K_ 14
#define H_ 8
#define DH_ 16
#define C2_ (2*C_)
#define R2 0.25f

// -------------------- kernel 1: per-point geometry --------------------
__global__ void geom_kernel(const float* __restrict__ pts,
                            const float* __restrict__ cav,
                            unsigned short* __restrict__ mask,
                            unsigned char* __restrict__ nearest) {
    __shared__ float cx[K_], cy[K_], cz[K_];
    int tid = threadIdx.x;
    if (tid < K_) {
        cx[tid] = cav[tid*3+0];
        cy[tid] = cav[tid*3+1];
        cz[tid] = cav[tid*3+2];
    }
    __syncthreads();
    int p = blockIdx.x * blockDim.x + tid;
    if (p >= P_) return;
    float px = pts[p*3+0], py = pts[p*3+1], pz = pts[p*3+2];
    unsigned m = 0;
    float best = 1e30f;
    int bi = 0;
    #pragma unroll
    for (int k = 0; k < K_; ++k) {
        float dx = px - cx[k], dy = py - cy[k], dz = pz - cz[k];
        float d2 = dx*dx + dy*dy + dz*dz;
        if (d2 < R2) m |= (1u << k);
        if (d2 < best) { best = d2; bi = k; }
    }
    mask[p] = (unsigned short)m;
    nearest[p] = (unsigned char)bi;
}

// -------------------- kernel 2: per-cavity counts (1 block) --------------------
__global__ void count_kernel(const unsigned short* __restrict__ mask,
                             int* __restrict__ counts) {
    __shared__ int sm[K_];
    int tid = threadIdx.x;
    if (tid < K_) sm[tid] = 0;
    __syncthreads();
    int acc[K_];
    #pragma unroll
    for (int k = 0; k < K_; ++k) acc[k] = 0;
    for (int p = tid; p < P_; p += 256) {
        unsigned m = mask[p];
        #pragma unroll
        for (int k = 0; k < K_; ++k) acc[k] += (m >> k) & 1u;
    }
    #pragma unroll
    for (int k = 0; k < K_; ++k) atomicAdd(&sm[k], acc[k]);
    __syncthreads();
    if (tid < K_) counts[tid] = sm[tid];
}

// -------------------- kernel 3: masked pooling sums --------------------
// grid = B*C blocks; block 256 threads; one block owns one (b,c) row.
__global__ void pool_kernel(const float* __restrict__ x,
                            const unsigned short* __restrict__ mask,
                            float* __restrict__ sums) {
    int row = blockIdx.x;             // b*C + c
    int b = row >> 7, c = row & (C_-1);
    int tid = threadIdx.x;
    const float4* xr = (const float4*)(x + (size_t)row * P_);
    const ushort4* mr = (const ushort4*)mask;
    float acc[K_];
    #pragma unroll
    for (int k = 0; k < K_; ++k) acc[k] = 0.f;
    for (int i = tid; i < P_/4; i += 256) {
        float4 xv = xr[i];
        ushort4 mv = mr[i];
        #pragma unroll
        for (int k = 0; k < K_; ++k) {
            if ((mv.x >> k) & 1) acc[k] += xv.x;
            if ((mv.y >> k) & 1) acc[k] += xv.y;
            if ((mv.z >> k) & 1) acc[k] += xv.z;
            if ((mv.w >> k) & 1) acc[k] += xv.w;
        }
    }
    // wave reduce (64 lanes) then cross-wave via LDS
    int lane = tid & 63, wave = tid >> 6;
    #pragma unroll
    for (int k = 0; k < K_; ++k) {
        float v = acc[k];
        #pragma unroll
        for (int off = 32; off > 0; off >>= 1) v += __shfl_down(v, off);
        acc[k] = v;
    }
    __shared__ float lsum[4][K_];
    if (lane == 0) {
        #pragma unroll
        for (int k = 0; k < K_; ++k) lsum[wave][k] = acc[k];
    }
    __syncthreads();
    if (tid < K_) {
        float t = lsum[0][tid] + lsum[1][tid] + lsum[2][tid] + lsum[3][tid];
        sums[((size_t)b*K_ + tid)*C_ + c] = t;
    }
}

// -------------------- kernel 4: feat + per-cavity MLP --------------------
// grid = B*K blocks, 256 threads
__global__ void mlp_kernel(const float* __restrict__ sums,
                           const int* __restrict__ counts,
                           const float* __restrict__ w1,
                           const float* __restrict__ b1,
                           const float* __restrict__ w2,
                           const float* __restrict__ b2,
                           float* __restrict__ proc) {
    int b = blockIdx.x / K_, k = blockIdx.x % K_;
    int tid = threadIdx.x;
    __shared__ float feat[C_];
    __shared__ float h[C2_];
    int cnt = counts[k];
    float inv = (cnt > 0) ? (1.f / (float)cnt) : 0.f;
    if (tid < C_) feat[tid] = sums[((size_t)b*K_ + k)*C_ + tid] * inv;
    __syncthreads();
    // layer1: h[d] = relu(b1 + feat . w1[k,d,:])   d in [0,256)
    {
        const float* w1r = w1 + ((size_t)k*C2_ + tid)*C_;
        float a = b1[k*C2_ + tid];
        #pragma unroll 8
        for (int c = 0; c < C_; ++c) a += feat[c] * w1r[c];
        h[tid] = fmaxf(a, 0.f);
    }
    __syncthreads();
    // layer2: proc[c] = tanh(b2 + h . w2[k,c,:])  c in [0,128)
    if (tid < C_) {
        const float* w2r = w2 + ((size_t)k*C_ + tid)*C2_;
        float a = b2[k*C_ + tid];
        #pragma unroll 8
        for (int d = 0; d < C2_; ++d) a += h[d] * w2r[d];
        proc[((size_t)b*K_ + k)*C_ + tid] = tanhf(a);
    }
}

// -------------------- kernel 5: MHA over K cavities + out proj --------------------
// grid = B blocks, 256 threads
__global__ void attn_kernel(const float* __restrict__ proc,
                            const float* __restrict__ in_w,
                            const float* __restrict__ in_b,
                            const float* __restrict__ out_w,
                            const float* __restrict__ out_b,
                            float* __restrict__ att) {
    int b = blockIdx.x;
    int tid = threadIdx.x;
    __shared__ float pr[K_][C_];
    __shared__ float qkv[K_][3*C_];
    __shared__ float ov[K_][C_];
    for (int i = tid; i < K_*C_; i += 256) pr[i / C_][i % C_] = proc[(size_t)b*K_*C_ + i];
    __syncthreads();
    // qkv[k,e] = in_b[e] + sum_c pr[k][c]*in_w[e,c]
    for (int i = tid; i < K_*3*C_; i += 256) {
        int kk = i / (3*C_), e = i % (3*C_);
        const float* wr = in_w + (size_t)e*C_;
        float a = in_b[e];
        #pragma unroll 8
        for (int c = 0; c < C_; ++c) a += pr[kk][c] * wr[c];
        qkv[kk][e] = a;
    }
    __syncthreads();
    // attention rows: (h,q) pairs = 8*14 = 112
    if (tid < H_*K_) {
        int hh = tid / K_, q = tid % K_;
        const float* qv = &qkv[q][hh*DH_];
        float sc[K_];
        float mx = -1e30f;
        #pragma unroll
        for (int kk = 0; kk < K_; ++kk) {
            float a = 0.f;
            #pragma unroll
            for (int d = 0; d < DH_; ++d) a += qv[d] * qkv[kk][C_ + hh*DH_ + d];
            a *= 0.25f;   // 1/sqrt(16)
            sc[kk] = a;
            mx = fmaxf(mx, a);
        }
        float ssum = 0.f;
        #pragma unroll
        for (int kk = 0; kk < K_; ++kk) { sc[kk] = __expf(sc[kk] - mx); ssum += sc[kk]; }
        float rinv = 1.f / ssum;
        #pragma unroll
        for (int d = 0; d < DH_; ++d) {
            float a = 0.f;
            #pragma unroll
            for (int kk = 0; kk < K_; ++kk) a += sc[kk] * qkv[kk][2*C_ + hh*DH_ + d];
            ov[q][hh*DH_ + d] = a * rinv;
        }
    }
    __syncthreads();
    // out proj: att[b,k,o] = out_b[o] + sum_c ov[k][c]*out_w[o,c]
    for (int i = tid; i < K_*C_; i += 256) {
        int kk = i / C_, o = i % C_;
        const float* wr = out_w + (size_t)o*C_;
        float a = out_b[o];
        #pragma unroll 8
        for (int c = 0; c < C_; ++c) a += ov[kk][c] * wr[c];
        att[((size_t)b*K_ + kk)*C_ + o] = a;
    }
}

// -------------------- kernel 6: gather-add back to points --------------------
// grid = (ceil(P/4/256), B*C), 256 threads
__global__ void gather_kernel(const float* __restrict__ x,
                              const float* __restrict__ att,
                              const unsigned char* __restrict__ nearest,
                              float* __restrict__ out) {
    int row = blockIdx.y;            // b*C + c
    int b = row >> 7, c = row & (C_-1);
    __shared__ float al[K_];
    if (threadIdx.x < K_) al[threadIdx.x] = att[((size_t)b*K_ + threadIdx.x)*C_ + c];
    __syncthreads();
    int i = blockIdx.x * blockDim.x + threadIdx.x;
    if (i >= P_/4) return;
    const float4* xr = (const float4*)(x + (size_t)row * P_);
    float4* orow = (float4*)(out + (size_t)row * P_);
    float4 xv = xr[i];
    uchar4 nv = ((const uchar4*)nearest)[i];
    float4 o;
    o.x = xv.x + al[nv.x];
    o.y = xv.y + al[nv.y];
    o.z = xv.z + al[nv.z];
    o.w = xv.w + al[nv.w];
    orow[i] = o;
}

extern "C" void kernel_launch(void* const* d_in, const int* in_sizes, int n_in,
                              void* d_out, int out_size, void* d_ws, size_t ws_size,
                              hipStream_t stream) {
    const float* x      = (const float*)d_in[0];
    const float* points = (const float*)d_in[1];
    const float* cav    = (const float*)d_in[2];
    const float* w1     = (const float*)d_in[3];
    const float* b1     = (const float*)d_in[4];
    const float* w2     = (const float*)d_in[5];
    const float* b2     = (const float*)d_in[6];
    const float* in_w   = (const float*)d_in[7];
    const float* in_b   = (const float*)d_in[8];
    const float* out_w  = (const float*)d_in[9];
    const float* out_b  = (const float*)d_in[10];
    float* out = (float*)d_out;

    // workspace carve (all offsets 256B-aligned)
    char* w = (char*)d_ws;
    unsigned short* mask    = (unsigned short*)(w + 0);        // 200000 B
    unsigned char*  nearest = (unsigned char*)(w + 200192);    // 100000 B
    int*            counts  = (int*)(w + 300288);              // 56 B
    float*          sums    = (float*)(w + 300544);            // 57344 B
    float*          procb   = (float*)(w + 358144);            // 57344 B
    float*          att     = (float*)(w + 415744);            // 57344 B

    geom_kernel<<<(P_ + 255)/256, 256, 0, stream>>>(points, cav, mask, nearest);
    count_kernel<<<1, 256, 0, stream>>>(mask, counts);
    pool_kernel<<<B_*C_, 256, 0, stream>>>(x, mask, sums);
    mlp_kernel<<<B_*K_, 256, 0, stream>>>(sums, counts, w1, b1, w2, b2, procb);
    attn_kernel<<<B_, 256, 0, stream>>>(procb, in_w, in_b, out_w, out_b, att);
    gather_kernel<<<dim3((P_/4 + 255)/256, B_*C_), 256, 0, stream>>>(x, att, nearest, out);
}

// Round 2
// 352.408 us; speedup vs baseline: 1.6254x; 1.6254x over previous
//
#include <hip/hip_runtime.h>
#include <hip/hip_bf16.h>
#include <math.h>

#define B_ 8
#define C_ 128
#define P_ 100000
#define K_ 14
#define H_ 8
#define DH_ 16
#define C2_ (2*C_)
#define E3_ (3*C_)
#define R2 0.25f

__device__ __forceinline__ int bitsel(unsigned m, int k) {
#if __has_builtin(__builtin_amdgcn_sbfe)
    return __builtin_amdgcn_sbfe((int)m, (unsigned)k, 1u);
#else
    return ((int)(m << (31 - k))) >> 31;
#endif
}

// -------------------- kernel 1: per-point geometry + fused counts --------------------
__global__ void geom_kernel(const float* __restrict__ pts,
                            const float* __restrict__ cav,
                            unsigned short* __restrict__ mask,
                            unsigned char* __restrict__ nearest,
                            int* __restrict__ counts) {
    __shared__ float cx[K_], cy[K_], cz[K_];
    __shared__ int sm[K_];
    int tid = threadIdx.x;
    if (tid < K_) {
        cx[tid] = cav[tid*3+0];
        cy[tid] = cav[tid*3+1];
        cz[tid] = cav[tid*3+2];
        sm[tid] = 0;
    }
    __syncthreads();
    int p = blockIdx.x * blockDim.x + tid;
    bool valid = (p < P_);
    int pc = valid ? p : (P_ - 1);
    float px = pts[pc*3+0], py = pts[pc*3+1], pz = pts[pc*3+2];
    unsigned m = 0;
    float best = 1e30f;
    int bi = 0;
    #pragma unroll
    for (int k = 0; k < K_; ++k) {
        float dx = px - cx[k], dy = py - cy[k], dz = pz - cz[k];
        float d2 = dx*dx + dy*dy + dz*dz;
        if (d2 < R2) m |= (1u << k);
        if (d2 < best) { best = d2; bi = k; }
    }
    if (!valid) m = 0;
    if (valid) {
        mask[p] = (unsigned short)m;
        nearest[p] = (unsigned char)bi;
    }
    // per-wave popcount per cavity -> LDS -> one global atomic per cavity per block
    int lane = tid & 63;
    #pragma unroll
    for (int k = 0; k < K_; ++k) {
        unsigned long long bal = __ballot((m >> k) & 1u);
        if (lane == 0) atomicAdd(&sm[k], (int)__popcll(bal));
    }
    __syncthreads();
    if (tid < K_) atomicAdd(&counts[tid], sm[tid]);
}

// -------------------- kernel 2: masked pooling sums --------------------
// grid = B*C blocks; block 256 threads; one block owns one (b,c) row.
__global__ void pool_kernel(const float* __restrict__ x,
                            const unsigned short* __restrict__ mask,
                            float* __restrict__ sums) {
    int row = blockIdx.x;             // b*C + c
    int b = row >> 7, c = row & (C_-1);
    int tid = threadIdx.x;
    const float4* xr = (const float4*)(x + (size_t)row * P_);
    const ushort4* mr = (const ushort4*)mask;
    float acc[K_];
    #pragma unroll
    for (int k = 0; k < K_; ++k) acc[k] = 0.f;
    for (int i = tid; i < P_/4; i += 256) {
        float4 xv = xr[i];
        ushort4 mv = mr[i];
        unsigned mx = mv.x, my = mv.y, mz = mv.z, mw = mv.w;
        int bx = __float_as_int(xv.x), by = __float_as_int(xv.y);
        int bz = __float_as_int(xv.z), bw = __float_as_int(xv.w);
        #pragma unroll
        for (int k = 0; k < K_; ++k) {
            acc[k] += __int_as_float(bitsel(mx, k) & bx);
            acc[k] += __int_as_float(bitsel(my, k) & by);
            acc[k] += __int_as_float(bitsel(mz, k) & bz);
            acc[k] += __int_as_float(bitsel(mw, k) & bw);
        }
    }
    // wave reduce (64 lanes) then cross-wave via LDS
    int lane = tid & 63, wave = tid >> 6;
    #pragma unroll
    for (int k = 0; k < K_; ++k) {
        float v = acc[k];
        #pragma unroll
        for (int off = 32; off > 0; off >>= 1) v += __shfl_down(v, off);
        acc[k] = v;
    }
    __shared__ float lsum[4][K_];
    if (lane == 0) {
        #pragma unroll
        for (int k = 0; k < K_; ++k) lsum[wave][k] = acc[k];
    }
    __syncthreads();
    if (tid < K_) {
        float t = lsum[0][tid] + lsum[1][tid] + lsum[2][tid] + lsum[3][tid];
        sums[((size_t)b*K_ + tid)*C_ + c] = t;
    }
}

// -------------------- kernel 3: feat + per-cavity MLP + qkv projection --------------------
// grid = B*K blocks, 256 threads
__global__ void mlp_kernel(const float* __restrict__ sums,
                           const int* __restrict__ counts,
                           const float* __restrict__ w1,
                           const float* __restrict__ b1,
                           const float* __restrict__ w2,
                           const float* __restrict__ b2,
                           const float* __restrict__ in_w,
                           const float* __restrict__ in_b,
                           float* __restrict__ qkv_out) {
    int b = blockIdx.x / K_, k = blockIdx.x % K_;
    int tid = threadIdx.x;
    __shared__ float feat[C_];
    __shared__ float h[C2_];
    __shared__ float pr[C_];
    int cnt = counts[k];
    float inv = (cnt > 0) ? (1.f / (float)cnt) : 0.f;
    if (tid < C_) feat[tid] = sums[((size_t)b*K_ + k)*C_ + tid] * inv;
    __syncthreads();
    // layer1: h[d] = relu(b1 + feat . w1[k,d,:])   d in [0,256)
    {
        const float* w1r = w1 + ((size_t)k*C2_ + tid)*C_;
        float a = b1[k*C2_ + tid];
        #pragma unroll 8
        for (int c = 0; c < C_; ++c) a += feat[c] * w1r[c];
        h[tid] = fmaxf(a, 0.f);
    }
    __syncthreads();
    // layer2: pr[c] = tanh(b2 + h . w2[k,c,:])  c in [0,128)
    if (tid < C_) {
        const float* w2r = w2 + ((size_t)k*C_ + tid)*C2_;
        float a = b2[k*C_ + tid];
        #pragma unroll 8
        for (int d = 0; d < C2_; ++d) a += h[d] * w2r[d];
        pr[tid] = tanhf(a);
    }
    __syncthreads();
    // qkv: qkv_out[b,k,e] = in_b[e] + pr . in_w[e,:]
    for (int e = tid; e < E3_; e += 256) {
        const float* wr = in_w + (size_t)e*C_;
        float a = in_b[e];
        #pragma unroll 8
        for (int c = 0; c < C_; ++c) a += pr[c] * wr[c];
        qkv_out[((size_t)b*K_ + k)*E3_ + e] = a;
    }
}

// -------------------- kernel 4: MHA over K cavities + out proj --------------------
// grid = B blocks, 256 threads
__global__ void attn_kernel(const float* __restrict__ qkv_in,
                            const float* __restrict__ out_w,
                            const float* __restrict__ out_b,
                            float* __restrict__ att) {
    int b = blockIdx.x;
    int tid = threadIdx.x;
    __shared__ float qkv[K_][E3_];
    __shared__ float ov[K_][C_];
    for (int i = tid; i < K_*E3_; i += 256) qkv[i / E3_][i % E3_] = qkv_in[(size_t)b*K_*E3_ + i];
    __syncthreads();
    // attention rows: (h,q) pairs = 8*14 = 112
    if (tid < H_*K_) {
        int hh = tid / K_, q = tid % K_;
        const float* qv = &qkv[q][hh*DH_];
        float sc[K_];
        float mx = -1e30f;
        #pragma unroll
        for (int kk = 0; kk < K_; ++kk) {
            float a = 0.f;
            #pragma unroll
            for (int d = 0; d < DH_; ++d) a += qv[d] * qkv[kk][C_ + hh*DH_ + d];
            a *= 0.25f;   // 1/sqrt(16)
            sc[kk] = a;
            mx = fmaxf(mx, a);
        }
        float ssum = 0.f;
        #pragma unroll
        for (int kk = 0; kk < K_; ++kk) { sc[kk] = __expf(sc[kk] - mx); ssum += sc[kk]; }
        float rinv = 1.f / ssum;
        #pragma unroll
        for (int d = 0; d < DH_; ++d) {
            float a = 0.f;
            #pragma unroll
            for (int kk = 0; kk < K_; ++kk) a += sc[kk] * qkv[kk][2*C_ + hh*DH_ + d];
            ov[q][hh*DH_ + d] = a * rinv;
        }
    }
    __syncthreads();
    // out proj: att[b,k,o] = out_b[o] + sum_c ov[k][c]*out_w[o,c]
    for (int i = tid; i < K_*C_; i += 256) {
        int kk = i / C_, o = i % C_;
        const float* wr = out_w + (size_t)o*C_;
        float a = out_b[o];
        #pragma unroll 8
        for (int c = 0; c < C_; ++c) a += ov[kk][c] * wr[c];
        att[((size_t)b*K_ + kk)*C_ + o] = a;
    }
}

// -------------------- kernel 5: gather-add back to points --------------------
// grid = (13, B*C), 256 threads, stride loop
__global__ void gather_kernel(const float* __restrict__ x,
                              const float* __restrict__ att,
                              const unsigned char* __restrict__ nearest,
                              float* __restrict__ out) {
    int row = blockIdx.y;            // b*C + c
    int b = row >> 7, c = row & (C_-1);
    __shared__ float al[K_];
    if (threadIdx.x < K_) al[threadIdx.x] = att[((size_t)b*K_ + threadIdx.x)*C_ + c];
    __syncthreads();
    const float4* xr = (const float4*)(x + (size_t)row * P_);
    float4* orow = (float4*)(out + (size_t)row * P_);
    const uchar4* nr = (const uchar4*)nearest;
    for (int i = blockIdx.x * blockDim.x + threadIdx.x; i < P_/4; i += 13*256) {
        float4 xv = xr[i];
        uchar4 nv = nr[i];
        float4 o;
        o.x = xv.x + al[nv.x];
        o.y = xv.y + al[nv.y];
        o.z = xv.z + al[nv.z];
        o.w = xv.w + al[nv.w];
        orow[i] = o;
    }
}

extern "C" void kernel_launch(void* const* d_in, const int* in_sizes, int n_in,
                              void* d_out, int out_size, void* d_ws, size_t ws_size,
                              hipStream_t stream) {
    const float* x      = (const float*)d_in[0];
    const float* points = (const float*)d_in[1];
    const float* cav    = (const float*)d_in[2];
    const float* w1     = (const float*)d_in[3];
    const float* b1     = (const float*)d_in[4];
    const float* w2     = (const float*)d_in[5];
    const float* b2     = (const float*)d_in[6];
    const float* in_w   = (const float*)d_in[7];
    const float* in_b   = (const float*)d_in[8];
    const float* out_w  = (const float*)d_in[9];
    const float* out_b  = (const float*)d_in[10];
    float* out = (float*)d_out;

    // workspace carve (all offsets 256B-aligned)
    char* w = (char*)d_ws;
    unsigned short* mask    = (unsigned short*)(w + 0);        // 200000 B
    unsigned char*  nearest = (unsigned char*)(w + 200192);    // 100000 B
    int*            counts  = (int*)(w + 300288);              // 56 B
    float*          sums    = (float*)(w + 300544);            // 57344 B
    float*          qkv     = (float*)(w + 358144);            // 172032 B
    float*          att     = (float*)(w + 530432);            // 57344 B

    hipMemsetAsync(counts, 0, K_ * sizeof(int), stream);
    geom_kernel<<<(P_ + 255)/256, 256, 0, stream>>>(points, cav, mask, nearest, counts);
    pool_kernel<<<B_*C_, 256, 0, stream>>>(x, mask, sums);
    mlp_kernel<<<B_*K_, 256, 0, stream>>>(sums, counts, w1, b1, w2, b2, in_w, in_b, qkv);
    attn_kernel<<<B_, 256, 0, stream>>>(qkv, out_w, out_b, att);
    gather_kernel<<<dim3(13, B_*C_), 256, 0, stream>>>(x, att, nearest, out);
}